// Round 3
// baseline (85.140 us; speedup 1.0000x reference)
//
#include <hip/hip_runtime.h>

namespace {
constexpr int N   = 64;
constexpr int D   = 32;
constexpr int PD  = 36;   // padded ind row (dwords): measured conflict-free (r1/r2)
constexpr int SHP = 72;   // sh row pad: 72%32==8 conflict-free residue (r11-r17)
constexpr int SCP = 65;   // sc row pad: stride 65 -> bank (lane+row)%32, 2-way max
constexpr float LOG2E = 1.4426950408889634f;
constexpr float LN2   = 0.6931471805599453f;

typedef float f32x2 __attribute__((ext_vector_type(2)));

#if __has_builtin(__builtin_amdgcn_exp2f)
__device__ __forceinline__ float fexp2(float x) { return __builtin_amdgcn_exp2f(x); }
#else
__device__ __forceinline__ float fexp2(float x) { return exp2f(x); }
#endif
#if __has_builtin(__builtin_amdgcn_rcpf)
__device__ __forceinline__ float frcp(float x) { return __builtin_amdgcn_rcpf(x); }
#else
__device__ __forceinline__ float frcp(float x) { return 1.0f / x; }
#endif
__device__ __forceinline__ void wavebar() {
#if __has_builtin(__builtin_amdgcn_wave_barrier)
    __builtin_amdgcn_wave_barrier();
#endif
}

// r19: LANE=i SCORE RESTRUCTURE. r16-r18 evidence: fused ~39-41us flat across
// occupancy 4/6/8 waves/SIMD and 2x redundancy removal -> intra-wave
// serial-latency bound. Culprit: 16 s_cbranch-separated SCORE_BODYs, each
// starting with s_loads it immediately consumes; branch boundaries block
// cross-body prefetch -> ~16 x (lgkmcnt wait + issue) serial chain per wave.
// Fix: score phase with lane=i, loop over the wave's 8 j's:
//   - b-side ind1[i=lane,:] in VGPRs ONCE (u1n/u1p split, reuses gate's wv)
//   - a-side u0[j,:] wave-uniform -> s_load, manual DOUBLE-BUFFER: j+1 quads
//     issue before j's compute (T14 issue-early / consume-late)
//   - sign-split on s1[j] (wave-uniform s_cmp): 8 branches/wave, loads hoisted
//     above the branch; per-pair math unchanged (9 pk + 2 exp):
//     elup1(a)*elup1(b) = exp2(min(aL,0)+min(bL,0))*(1+max(aL,0)ln2)*(1+max(bL,0)ln2)
//   - sc -> sc_lds[j][i] (pad 65: both write (row j, lanes consec) and read
//     (stride-65 column) are <=2-way = free, m136)
// + barrier 2, then r17-verified softmax/gate/phase-2 unchanged (lane=j).
// LDS 63488 B -> 2 blocks/CU = 4 waves/SIMD (same as r17: clean structural A/B).
__global__ __launch_bounds__(512, 4) void fused(
        const float* __restrict__ feature,
        const float* __restrict__ ind,
        float* __restrict__ out) {
    __shared__ float ind_lds[3][N][PD];   // 27648 B
    __shared__ float s_lds[3][N];         //   768 B
    __shared__ float sc_lds[N][SCP];      // 16640 B  [j][i]
    __shared__ float sh_lds[N][SHP];      // 18432 B  total 63488 B -> 2 blocks/CU

    const int t    = threadIdx.x;
    const int lane = t & 63;
    const int wave = t >> 6;
    const int b    = blockIdx.x;

    // ---- stage indicator: 1536 float4, 3 per thread, coalesced ----
    {
        const float4* src = reinterpret_cast<const float4*>(ind);
#pragma unroll
        for (int idx = t; idx < 3 * N * D / 4; idx += 512) {
            int a = idx >> 9;
            int r = idx & 511;
            int n = r >> 3;
            int k = r & 7;
            *reinterpret_cast<float4*>(&ind_lds[a][n][k * 4]) = src[idx];
        }
    }

    // ---- s[a][n] = feature[b,n,:] . ind[a,n,:] from GLOBAL, overlapped with
    //      staging (single staging barrier; r13-verified) ----
    if (t < 3 * N) {
        int a = t >> 6, n = t & 63;
        const float4* frow = reinterpret_cast<const float4*>(feature + ((size_t)b * N + n) * D);
        const float4* irow = reinterpret_cast<const float4*>(ind + (a * N + n) * D);
        f32x2 sa2 = {0.f, 0.f};
#pragma unroll
        for (int k = 0; k < 8; ++k) {
            float4 f4 = frow[k];
            float4 i4 = irow[k];
            sa2 = __builtin_elementwise_fma(f32x2{f4.x, f4.y}, f32x2{i4.x, i4.y}, sa2);
            sa2 = __builtin_elementwise_fma(f32x2{f4.z, f4.w}, f32x2{i4.z, i4.w}, sa2);
        }
        s_lds[a][n] = sa2.x + sa2.y;
    }
    __syncthreads();   // barrier 1

    // wave-uniform row indices (readfirstlane -> SGPR -> s_load addresses);
    // used both as gate i-rows and as this wave's j-slice in the score phase
    int igu[8];
#pragma unroll
    for (int r = 0; r < 8; ++r)
        igu[r] = __builtin_amdgcn_readfirstlane(wave * 8 + r);

    const f32x2 ln2v = {LN2, LN2};
    const f32x2 onev = {1.0f, 1.0f};
    const f32x2 zerv = {0.0f, 0.0f};

    // ---- gate bitmasks (lane=j) + u1 sign-split arrays (lane=i) ----
    // Both consume ind1[lane,:] -> read once as wv, derive u1n/u1p from it.
    unsigned long long gmask[8];
    f32x2 u1n[16], u1p[16];
    {
        f32x2 wv[16];
#pragma unroll
        for (int k4 = 0; k4 < 8; ++k4) {
            float4 w4 = *reinterpret_cast<const float4*>(&ind_lds[1][lane][k4 * 4]);
            wv[k4 * 2 + 0] = f32x2{w4.x, w4.y};
            wv[k4 * 2 + 1] = f32x2{w4.z, w4.w};
        }
#pragma unroll
        for (int r = 0; r < 8; ++r) {
            f32x2 ga = {0.f, 0.f};
#pragma unroll
            for (int k4 = 0; k4 < 8; ++k4) {
                float4 a4 = *reinterpret_cast<const float4*>(ind + igu[r] * D + k4 * 4);  // s_load
                ga = __builtin_elementwise_fma(f32x2{a4.x, a4.y}, wv[k4 * 2 + 0], ga);
                ga = __builtin_elementwise_fma(f32x2{a4.z, a4.w}, wv[k4 * 2 + 1], ga);
            }
            gmask[r] = __ballot(ga.x + ga.y > 0.f);
        }
#pragma unroll
        for (int k = 0; k < 16; ++k) {
            f32x2 nn = __builtin_elementwise_min(wv[k], zerv);
            u1n[k] = nn;
            u1p[k] = wv[k] - nn;
        }
    }

    // ---- score phase: lane = i, loop over this wave's 8 j's ----
    {
        const float s0Ls = s_lds[0][lane] * LOG2E;   // per-lane (lane = i)
        const f32x2 s0L2 = {s0Ls, s0Ls};

        float4 buf[2][8];   // double-buffered u0[j,:] (wave-uniform -> s_load)
#pragma unroll
        for (int k = 0; k < 8; ++k)
            buf[0][k] = *reinterpret_cast<const float4*>(ind + igu[0] * D + k * 4);

#pragma unroll
        for (int jj = 0; jj < 8; ++jj) {
            // prefetch next j row before this j's compute (latency hidden)
            if (jj < 7) {
#pragma unroll
                for (int k = 0; k < 8; ++k)
                    buf[(jj + 1) & 1][k] =
                        *reinterpret_cast<const float4*>(ind + igu[jj + 1] * D + k * 4);
            }
            const int jgl = wave * 8 + jj;
            const float s1raw = s_lds[1][jgl];   // uniform ds_read (broadcast)
            const float s1u = __uint_as_float(
                __builtin_amdgcn_readfirstlane(__float_as_uint(s1raw)));
            const float s1e = s1u * LOG2E;
            const f32x2 s1v  = {s1u, s1u};
            const f32x2 s1ev = {s1e, s1e};
            f32x2 acc = {0.f, 0.f};

#define SBODY(UN, UP)                                                           \
    {                                                                           \
        _Pragma("unroll")                                                       \
        for (int k4 = 0; k4 < 8; ++k4) {                                        \
            const float4 c4 = buf[jj & 1][k4];                                  \
            const f32x2 u0a = {c4.x, c4.y};                                     \
            const f32x2 u0b = {c4.z, c4.w};                                     \
            _Pragma("unroll")                                                   \
            for (int h = 0; h < 2; ++h) {                                       \
                const f32x2 u0 = h ? u0b : u0a;                                 \
                f32x2 aL = s0L2 * u0;                                           \
                f32x2 an = __builtin_elementwise_min(aL, zerv);                 \
                f32x2 Af = __builtin_elementwise_fma(aL - an, ln2v, onev);      \
                f32x2 bn = s1ev * UN[k4 * 2 + h];                               \
                f32x2 Bf = __builtin_elementwise_fma(s1v, UP[k4 * 2 + h], onev);\
                f32x2 mn = an + bn;                                             \
                f32x2 E  = {fexp2(mn.x), fexp2(mn.y)};                          \
                acc = __builtin_elementwise_fma(E, Af * Bf, acc);               \
            }                                                                   \
        }                                                                       \
    }
            // wave-uniform sign split on s1[j]:
            //  s1>=0: bL<0 iff u1<0 -> bn = s1e*u1n; max(bL,0)*ln2 = s1*u1p
            //  s1< 0: bL<0 iff u1>0 -> bn = s1e*u1p; max(bL,0)*ln2 = s1*u1n
            if (s1u >= 0.f) { SBODY(u1n, u1p) } else { SBODY(u1p, u1n) }
#undef SBODY

            sc_lds[jgl][lane] = acc.x + acc.y;   // row jgl, lanes consecutive
        }
    }
    __syncthreads();   // barrier 2 (score writers != softmax readers)

    // ---- softmax (lane = j), rows = wave*8+rr; scores from sc_lds[lane][row]
    //      (stride-65 column read: (lane*65+row)%32 = (lane+row)%32, 2-way) ----
    float score[8];
#pragma unroll
    for (int r = 0; r < 8; ++r) score[r] = sc_lds[lane][wave * 8 + r];

    float mx[8], e[8], sm[8];
#pragma unroll
    for (int r = 0; r < 8; ++r) mx[r] = score[r];
#pragma unroll
    for (int off = 32; off >= 1; off >>= 1) {
#pragma unroll
        for (int r = 0; r < 8; ++r) mx[r] = fmaxf(mx[r], __shfl_xor(mx[r], off));
    }
#pragma unroll
    for (int r = 0; r < 8; ++r) e[r] = fexp2((score[r] - mx[r]) * LOG2E);
#pragma unroll
    for (int r = 0; r < 8; ++r) sm[r] = e[r];
#pragma unroll
    for (int off = 32; off >= 1; off >>= 1) {
#pragma unroll
        for (int r = 0; r < 8; ++r) sm[r] += __shfl_xor(sm[r], off);
    }
#pragma unroll
    for (int r = 0; r < 8; ++r) {
        const int ig  = wave * 8 + r;
        const float g = (float)((gmask[r] >> lane) & 1ull);
        sh_lds[ig][lane] = (e[r] * g) * (s_lds[2][ig] * frcp(sm[r]));
    }

    // NO block barrier: wave w wrote sh rows 8w..8w+7 and phase 2's thread t
    // (row t>>3) reads only those rows (same-wave LDS RAW, lgkmcnt-ordered;
    // r13/r14/r17-verified pattern).
    wavebar();

    // ---- phase 2: out[i,:] = sh[i,:] @ ind2; thread = (i_loc, d-quad) ----
    {
        const int i_loc = t >> 3;
        const int dq    = t & 7;
        f32x2 acc0 = {0.f, 0.f}, acc1 = {0.f, 0.f};
#pragma unroll
        for (int j = 0; j < 64; j += 4) {
            float4 sh4 = *reinterpret_cast<const float4*>(&sh_lds[i_loc][j]);
#pragma unroll
            for (int c = 0; c < 4; ++c) {
                float4 v4 = *reinterpret_cast<const float4*>(&ind_lds[2][j + c][dq * 4]);
                float  w  = (&sh4.x)[c];
                f32x2 wvv = {w, w};
                acc0 = __builtin_elementwise_fma(wvv, f32x2{v4.x, v4.y}, acc0);
                acc1 = __builtin_elementwise_fma(wvv, f32x2{v4.z, v4.w}, acc1);
            }
        }
        float4 acc = {acc0.x, acc0.y, acc1.x, acc1.y};
        *reinterpret_cast<float4*>(out + ((size_t)b * N + i_loc) * D + dq * 4) = acc;
    }
}
}  // namespace

extern "C" void kernel_launch(void* const* d_in, const int* in_sizes, int n_in,
                              void* d_out, int out_size, void* d_ws, size_t ws_size,
                              hipStream_t stream) {
    const float* feature = (const float*)d_in[0];
    const float* ind     = (const float*)d_in[1];
    float*       out     = (float*)d_out;
    fused<<<512, 512, 0, stream>>>(feature, ind, out);
}